// Round 5
// baseline (266.287 us; speedup 1.0000x reference)
//
#include <hip/hip_runtime.h>

// RandomizedNodeLabeling — split 4-dispatch, column-sliced SpMMs (R4).
// N=100000 nodes, D=64, NADJ=1.6M sorted-row COO, E=262144 query edges.
//
// R4 theory: gathers are MSHR x latency bound (~3 TB/s effective random-line
// service). Lever = latency via L2 locality: process neighbors in column-range
// passes sized to fit per-XCD L2 (4 MB).
//   spmm1: 2 passes x 3.2 MB xw slice   (was ~62% L2 hit -> ~95%)
//   spmm2: 5 passes x 2.56 MB h1 slice  (was ~31% L2 hit -> ~90%)
// Adjacency re-scan per pass is cheap: each wave's segment (~0.5 KB) is
// L1-resident after pass 0. deg/dsum accumulated in pass 0 only.

#define D 64
#define NPASS1 2
#define NPASS2 5

typedef unsigned int uint32;
typedef _Float16 h2 __attribute__((ext_vector_type(2)));

union U32H2 { uint32 u; h2 h; };
__device__ __forceinline__ h2 u_as_h2(uint32 u) { U32H2 t; t.u = u; return t.h; }

__device__ __forceinline__ uint32 pack2(float a, float b) {
    // round-to-nearest-even bf16 pack: a -> lo16, b -> hi16
    uint32 ua = __float_as_uint(a);
    ua += 0x7fffu + ((ua >> 16) & 1u);
    uint32 ub = __float_as_uint(b);
    ub += 0x7fffu + ((ub >> 16) & 1u);
    return (ua >> 16) | (ub & 0xffff0000u);
}
__device__ __forceinline__ float lo2f(uint32 u) { return __uint_as_float(u << 16); }
__device__ __forceinline__ float hi2f(uint32 u) { return __uint_as_float(u & 0xffff0000u); }

// f32 -> e4m3 byte (RNE), input pre-scaled by 64. |v| <= 64 << 448 so no inf.
__device__ __forceinline__ uint32 enc1(float v) {
    float a = fabsf(v);
    uint32 s = (__float_as_uint(v) >> 24) & 0x80u;
    if (a >= 448.f) return s | 0x7Eu;              // clamp to max normal
    if (a < 0.015625f) {                           // denormal: m = RNE(a*512)
        uint32 m = (uint32)rintf(a * 512.f);
        return (m > 7u) ? (s | 0x08u) : (s | m);
    }
    uint32 b = __float_as_uint(a);
    b += 0x7FFFFu + ((b >> 20) & 1u);              // RNE at mantissa bit 20
    uint32 m3 = (b >> 20) & 7u;
    int e4 = (int)(b >> 23) - 127 + 7;
    if (e4 > 15) return s | 0x7Eu;
    return s | ((uint32)e4 << 3) | m3;
}

// uint32 of 4 e4m3 bytes -> two packed-f16 pairs (even bytes {0,2}, odd {1,3}),
// value = e4m3 * 2^-6 (rebias +2 instead of +8 folds the unscale).
__device__ __forceinline__ void dec8(uint32 u, uint32& pe, uint32& po) {
    uint32 se = (u << 8) & 0x80008000u;
    uint32 ue = u & 0x007f007fu;
    pe = ((ue << 7) + 0x08000800u) | se;
    uint32 so = u & 0x80008000u;
    uint32 uo = (u >> 8) & 0x007f007fu;
    po = ((uo << 7) + 0x08000800u) | so;
}

#define RED_GRP(v)  { v += __shfl_xor(v, 1, 64); v += __shfl_xor(v, 2, 64);  v += __shfl_xor(v, 4, 64);  }

// blocks [0, xw_blocks): xw_fp8 = enc(x*w*64). blocks [xw_blocks, ...): row_ptr.
__global__ void __launch_bounds__(256) prep_kernel(const float4* __restrict__ x,
                                                   const float* __restrict__ w,
                                                   uint2* __restrict__ xw,
                                                   const int* __restrict__ adj_row,
                                                   int* __restrict__ row_ptr,
                                                   int n8, int n, int nadj, int xw_blocks) {
    if ((int)blockIdx.x < xw_blocks) {
        int i = blockIdx.x * blockDim.x + threadIdx.x;   // over n*8 dim-groups
        if (i >= n8) return;
        float s = w[i >> 3] * 64.f;
        float4 a = x[i * 2], b = x[i * 2 + 1];
        // word0: b0=d0 b1=d2 b2=d1 b3=d3 ; word1: b0=d4 b1=d6 b2=d5 b3=d7
        uint32 w0 = enc1(a.x * s) | (enc1(a.z * s) << 8)
                  | (enc1(a.y * s) << 16) | (enc1(a.w * s) << 24);
        uint32 w1 = enc1(b.x * s) | (enc1(b.z * s) << 8)
                  | (enc1(b.y * s) << 16) | (enc1(b.w * s) << 24);
        xw[i] = make_uint2(w0, w1);
    } else {
        int i = (blockIdx.x - xw_blocks) * blockDim.x + threadIdx.x;
        if (i > n) return;
        int lo = 0, hi = nadj;                 // lower_bound(adj_row, i)
        while (lo < hi) {
            int mid = (lo + hi) >> 1;
            if (adj_row[mid] < i) lo = mid + 1; else hi = mid;
        }
        row_ptr[i] = lo;
    }
}

// one_hop = A*xw (fp8 src, packed-f16 accumulate -> bf16 dst); deg = degree.
// 2 column-slice passes: each pass's gather range (3.2 MB) fits per-XCD L2.
__global__ void __launch_bounds__(256) spmm1_kernel(const uint2* __restrict__ src,
                                                    const int* __restrict__ row_ptr,
                                                    const int* __restrict__ adj_col,
                                                    uint4* __restrict__ dst,
                                                    float* __restrict__ degout,
                                                    int n) {
    int lane = threadIdx.x & 63;
    int sub = lane & 7;
    int node = blockIdx.x * 32 + (threadIdx.x >> 6) * 8 + (lane >> 3);
    if (node >= n) return;
    int start = row_ptr[node], end = row_ptr[node + 1];
    int deg_n = end - start;
    h2 acc0 = u_as_h2(0u), acc1 = u_as_h2(0u), acc2 = u_as_h2(0u), acc3 = u_as_h2(0u);
    int gbase = lane & 56;
    const int* colp = adj_col + start;
    int slice = (n + NPASS1 - 1) / NPASS1;
    for (int p = 0; p < NPASS1; ++p) {
        int rlo = p * slice, rhi = rlo + slice;
        int base = 0;
        for (; base + 8 <= deg_n; base += 8) {     // full blocks
            int idx = colp[base + sub];
#pragma unroll
            for (int i = 0; i < 8; ++i) {
                int c = __shfl(idx, gbase + i, 64);
                if (c >= rlo && c < rhi) {
                    uint2 qv = src[(size_t)c * 8 + sub];
                    uint32 pe, po;
                    dec8(qv.x, pe, po);
                    acc0 += u_as_h2(pe); acc1 += u_as_h2(po);
                    dec8(qv.y, pe, po);
                    acc2 += u_as_h2(pe); acc3 += u_as_h2(po);
                }
            }
        }
        if (base < deg_n) {                        // tail: invalid lanes get c=-1
            int k = base + sub;
            int idx = (k < deg_n) ? colp[k] : -1;
#pragma unroll
            for (int i = 0; i < 8; ++i) {
                int c = __shfl(idx, gbase + i, 64);
                if (c >= rlo && c < rhi) {
                    uint2 qv = src[(size_t)c * 8 + sub];
                    uint32 pe, po;
                    dec8(qv.x, pe, po);
                    acc0 += u_as_h2(pe); acc1 += u_as_h2(po);
                    dec8(qv.y, pe, po);
                    acc2 += u_as_h2(pe); acc3 += u_as_h2(po);
                }
            }
        }
    }
    // acc0={d0,d1} acc1={d2,d3} acc2={d4,d5} acc3={d6,d7}
    uint4 o;
    o.x = pack2((float)acc0.x, (float)acc0.y);
    o.y = pack2((float)acc1.x, (float)acc1.y);
    o.z = pack2((float)acc2.x, (float)acc2.y);
    o.w = pack2((float)acc3.x, (float)acc3.y);
    dst[(size_t)node * 8 + sub] = o;
    if (sub == 0) degout[node] = (float)deg_n;
}

// two_iter = A*one_hop (bf16 src -> bf16 dst); degpair = {deg, deg2}.
// 5 column-slice passes: each pass's gather range (2.56 MB) fits per-XCD L2.
__global__ void __launch_bounds__(256) spmm2_kernel(const uint4* __restrict__ src,
                                                    const int* __restrict__ row_ptr,
                                                    const int* __restrict__ adj_col,
                                                    const float* __restrict__ degv,
                                                    uint4* __restrict__ dst,
                                                    float2* __restrict__ degpair,
                                                    int n) {
    int lane = threadIdx.x & 63;
    int sub = lane & 7;
    int node = blockIdx.x * 32 + (threadIdx.x >> 6) * 8 + (lane >> 3);
    if (node >= n) return;
    int start = row_ptr[node], end = row_ptr[node + 1];
    int deg_n = end - start;
    float a0 = 0.f, a1 = 0.f, a2 = 0.f, a3 = 0.f,
          a4 = 0.f, a5 = 0.f, a6 = 0.f, a7 = 0.f;
    float dsum = 0.f;
    int gbase = lane & 56;
    const int* colp = adj_col + start;
    int slice = (n + NPASS2 - 1) / NPASS2;
    for (int p = 0; p < NPASS2; ++p) {
        int rlo = p * slice, rhi = rlo + slice;
        int base = 0;
        for (; base + 8 <= deg_n; base += 8) {
            int idx = colp[base + sub];
            if (p == 0) dsum += degv[idx];         // deg sum once, pass 0
#pragma unroll
            for (int i = 0; i < 8; ++i) {
                int c = __shfl(idx, gbase + i, 64);
                if (c >= rlo && c < rhi) {
                    uint4 qv = src[(size_t)c * 8 + sub];
                    a0 += lo2f(qv.x); a1 += hi2f(qv.x);
                    a2 += lo2f(qv.y); a3 += hi2f(qv.y);
                    a4 += lo2f(qv.z); a5 += hi2f(qv.z);
                    a6 += lo2f(qv.w); a7 += hi2f(qv.w);
                }
            }
        }
        if (base < deg_n) {                        // tail: invalid lanes get c=-1
            int k = base + sub;
            bool kv = k < deg_n;
            int idx = kv ? colp[k] : -1;
            if (p == 0 && kv) dsum += degv[idx];
#pragma unroll
            for (int i = 0; i < 8; ++i) {
                int c = __shfl(idx, gbase + i, 64);
                if (c >= rlo && c < rhi) {
                    uint4 qv = src[(size_t)c * 8 + sub];
                    a0 += lo2f(qv.x); a1 += hi2f(qv.x);
                    a2 += lo2f(qv.y); a3 += hi2f(qv.y);
                    a4 += lo2f(qv.z); a5 += hi2f(qv.z);
                    a6 += lo2f(qv.w); a7 += hi2f(qv.w);
                }
            }
        }
    }
    uint4 o;
    o.x = pack2(a0, a1); o.y = pack2(a2, a3);
    o.z = pack2(a4, a5); o.w = pack2(a6, a7);
    dst[(size_t)node * 8 + sub] = o;
    RED_GRP(dsum)                              // sum over the group's 8 lanes
    if (sub == 0)
        degpair[node] = make_float2((float)deg_n,
                                    fmaxf(dsum - (float)deg_n - 1.0f, 0.0f));
}

__global__ void __launch_bounds__(256) edge_kernel(const int* __restrict__ edges, // [2,E]
                                                   const uint2* __restrict__ xw,
                                                   const uint4* __restrict__ h1,
                                                   const uint4* __restrict__ t2,
                                                   const float2* __restrict__ degpair,
                                                   float* __restrict__ out,
                                                   int E) {
    __shared__ float so[32 * 15];              // 32 edges/block x 15 features
    int t = blockIdx.x * blockDim.x + threadIdx.x;
    int q = t >> 3, sub = t & 7;               // 8 lanes per edge
    bool valid = q < E;
    if (valid) {
        int u = edges[q], v = edges[E + q];
        uint2 pxu = xw[(size_t)u * 8 + sub], pxv = xw[(size_t)v * 8 + sub];
        uint4 phu = h1[(size_t)u * 8 + sub], phv = h1[(size_t)v * 8 + sub];
        uint4 ptu = t2[(size_t)u * 8 + sub], ptv = t2[(size_t)v * 8 + sub];
        float2 dpu = degpair[u], dpv = degpair[v];
        float du = dpu.x, du2 = dpu.y, dv = dpv.x, dv2 = dpv.y;

        float fxu[8], fxv[8], fhu[8], fhv[8], ftu[8], ftv[8];
        {
            uint32 pe, po;
            dec8(pxu.x, pe, po);
            h2 e = u_as_h2(pe), o_ = u_as_h2(po);
            fxu[0] = (float)e.x; fxu[1] = (float)e.y; fxu[2] = (float)o_.x; fxu[3] = (float)o_.y;
            dec8(pxu.y, pe, po);
            e = u_as_h2(pe); o_ = u_as_h2(po);
            fxu[4] = (float)e.x; fxu[5] = (float)e.y; fxu[6] = (float)o_.x; fxu[7] = (float)o_.y;
            dec8(pxv.x, pe, po);
            e = u_as_h2(pe); o_ = u_as_h2(po);
            fxv[0] = (float)e.x; fxv[1] = (float)e.y; fxv[2] = (float)o_.x; fxv[3] = (float)o_.y;
            dec8(pxv.y, pe, po);
            e = u_as_h2(pe); o_ = u_as_h2(po);
            fxv[4] = (float)e.x; fxv[5] = (float)e.y; fxv[6] = (float)o_.x; fxv[7] = (float)o_.y;
        }
        fhu[0]=lo2f(phu.x); fhu[1]=hi2f(phu.x); fhu[2]=lo2f(phu.y); fhu[3]=hi2f(phu.y);
        fhu[4]=lo2f(phu.z); fhu[5]=hi2f(phu.z); fhu[6]=lo2f(phu.w); fhu[7]=hi2f(phu.w);
        fhv[0]=lo2f(phv.x); fhv[1]=hi2f(phv.x); fhv[2]=lo2f(phv.y); fhv[3]=hi2f(phv.y);
        fhv[4]=lo2f(phv.z); fhv[5]=hi2f(phv.z); fhv[6]=lo2f(phv.w); fhv[7]=hi2f(phv.w);
        ftu[0]=lo2f(ptu.x); ftu[1]=hi2f(ptu.x); ftu[2]=lo2f(ptu.y); ftu[3]=hi2f(ptu.y);
        ftu[4]=lo2f(ptu.z); ftu[5]=hi2f(ptu.z); ftu[6]=lo2f(ptu.w); ftu[7]=hi2f(ptu.w);
        ftv[0]=lo2f(ptv.x); ftv[1]=hi2f(ptv.x); ftv[2]=lo2f(ptv.y); ftv[3]=hi2f(ptv.y);
        ftv[4]=lo2f(ptv.z); ftv[5]=hi2f(ptv.z); ftv[6]=lo2f(ptv.w); ftv[7]=hi2f(ptv.w);

        float c11 = 0.f, c12 = 0.f, c21 = 0.f, c22 = 0.f,
              cc12 = 0.f, cc21 = 0.f, cc22 = 0.f, cs12 = 0.f, cs21 = 0.f;
#pragma unroll
        for (int j = 0; j < 8; ++j) {
            float xu = fxu[j], xv = fxv[j];
            float hu = fhu[j], hv = fhv[j];
            float tu = ftu[j], tv = ftv[j];
            float h2u = tu - hu - xu, h2v = tv - hv - xv;
            float au = fmaf(-du, xu, tu), av = fmaf(-dv, xv, tv);
            c11  = fmaf(hu,  hv,  c11);
            c12  = fmaf(hu,  h2v, c12);
            c21  = fmaf(h2u, hv,  c21);
            c22  = fmaf(h2u, h2v, c22);
            cc12 = fmaf(hu,  tv,  cc12);
            cc21 = fmaf(tu,  hv,  cc21);
            cc22 = fmaf(au,  av,  cc22);
            cs12 = fmaf(hu,  tu,  cs12);
            cs21 = fmaf(hv,  tv,  cs21);
        }
        RED_GRP(c11) RED_GRP(c12) RED_GRP(c21) RED_GRP(c22)
        RED_GRP(cc12) RED_GRP(cc21) RED_GRP(cc22) RED_GRP(cs12) RED_GRP(cs21)

        if (sub == 0) {
            float* o = so + (threadIdx.x >> 3) * 15;
            o[0]  = c11;
            o[1]  = c12;
            o[2]  = c21;
            o[3]  = c22;
            o[4]  = du + dv - 2.f * c11 - c12 - c21;
            o[5]  = du2 + dv2 - 2.f * c22 - c12 - c21;
            o[6]  = cc12;
            o[7]  = cc21;
            o[8]  = cc22;
            o[9]  = cs12;
            o[10] = cs21;
            o[11] = du;
            o[12] = dv;
            o[13] = du2;
            o[14] = dv2;
        }
    }
    __syncthreads();
    int eb = blockIdx.x * 32;                  // first edge of this block
    if (eb < E) {
        int nval = E - eb; if (nval > 32) nval = 32;
        int nflt = nval * 15;
        size_t obase = (size_t)eb * 15;
        for (int k = threadIdx.x; k < nflt; k += 256)
            out[obase + k] = so[k];            // fully coalesced
    }
}

extern "C" void kernel_launch(void* const* d_in, const int* in_sizes, int n_in,
                              void* d_out, int out_size, void* d_ws, size_t ws_size,
                              hipStream_t stream) {
    const float* x       = (const float*)d_in[0];
    const float* w       = (const float*)d_in[1];
    const int*   edges   = (const int*)d_in[2];
    const int*   adj_row = (const int*)d_in[3];
    const int*   adj_col = (const int*)d_in[4];

    const int N    = in_sizes[1];        // node_weight length
    const int E    = in_sizes[2] / 2;
    const int NADJ = in_sizes[3];

    char* ws = (char*)d_ws;
    size_t off = 0;
    auto take = [&](size_t bytes) {
        void* p = ws + off;
        off = (off + bytes + 255) & ~(size_t)255;
        return p;
    };
    uint2*  xw      = (uint2*)take((size_t)N * 8 * sizeof(uint2));  // fp8: 64 B/node
    uint4*  one_hop = (uint4*)take((size_t)N * D * 2);              // bf16: 128 B/node
    uint4*  two_it  = (uint4*)take((size_t)N * D * 2);
    float*  deg     = (float*)take((size_t)N * sizeof(float));
    float2* degpair = (float2*)take((size_t)N * sizeof(float2));
    int*    row_ptr = (int*)take((size_t)(N + 1) * sizeof(int));
    (void)ws_size;

    float* out = (float*)d_out;

    // 1. fused: xw fp8 encode + CSR row pointers
    {
        int n8 = N * 8;
        int xw_blocks = (n8 + 255) / 256;
        int rp_blocks = (N + 1 + 255) / 256;
        prep_kernel<<<xw_blocks + rp_blocks, 256, 0, stream>>>(
            (const float4*)x, w, xw, adj_row, row_ptr, n8, N, NADJ, xw_blocks);
    }
    // 2. one_hop + deg   (32 nodes per 256-thread block)
    spmm1_kernel<<<(N + 31) / 32, 256, 0, stream>>>(xw, row_ptr, adj_col, one_hop, deg, N);
    // 3. two_iter + degpair{deg,deg2}
    spmm2_kernel<<<(N + 31) / 32, 256, 0, stream>>>(one_hop, row_ptr, adj_col, deg,
                                                    two_it, degpair, N);
    // 4. edge features
    edge_kernel<<<((size_t)E * 8 + 255) / 256, 256, 0, stream>>>(edges, xw, one_hop, two_it,
                                                                 degpair, out, E);
}

// Round 6
// 184.567 us; speedup vs baseline: 1.4428x; 1.4428x over previous
//
#include <hip/hip_runtime.h>

// RandomizedNodeLabeling — fp8 xw AND fp8 one_hop tables (64 B/node each),
// bf16 two_iter. N=100000, D=64, NADJ=1.6M sorted-row COO, E=262144 edges.
//
// R5: gathers are rate-limited (~2.6 TB/s random-line service; MLP and
// locality levers both measured neutral/negative) -> cut bytes instead.
// one_hop stored as e4m3(h1*64), same byte layout as xw. spmm2 gathers
// 64 B/neighbor (was 128), edge h1 gather 64 B (was 128).
// Random traffic: 475 MB -> ~340 MB.

#define D 64

typedef unsigned int uint32;
typedef _Float16 h2 __attribute__((ext_vector_type(2)));

union U32H2 { uint32 u; h2 h; };
__device__ __forceinline__ h2 u_as_h2(uint32 u) { U32H2 t; t.u = u; return t.h; }

__device__ __forceinline__ uint32 pack2(float a, float b) {
    // round-to-nearest-even bf16 pack: a -> lo16, b -> hi16
    uint32 ua = __float_as_uint(a);
    ua += 0x7fffu + ((ua >> 16) & 1u);
    uint32 ub = __float_as_uint(b);
    ub += 0x7fffu + ((ub >> 16) & 1u);
    return (ua >> 16) | (ub & 0xffff0000u);
}
__device__ __forceinline__ float lo2f(uint32 u) { return __uint_as_float(u << 16); }
__device__ __forceinline__ float hi2f(uint32 u) { return __uint_as_float(u & 0xffff0000u); }

// f32 -> e4m3 byte (RNE), input pre-scaled by 64. |v| <= 448 so no inf.
__device__ __forceinline__ uint32 enc1(float v) {
    float a = fabsf(v);
    uint32 s = (__float_as_uint(v) >> 24) & 0x80u;
    if (a >= 448.f) return s | 0x7Eu;              // clamp to max normal
    if (a < 0.015625f) {                           // denormal: m = RNE(a*512)
        uint32 m = (uint32)rintf(a * 512.f);
        return (m > 7u) ? (s | 0x08u) : (s | m);
    }
    uint32 b = __float_as_uint(a);
    b += 0x7FFFFu + ((b >> 20) & 1u);              // RNE at mantissa bit 20
    uint32 m3 = (b >> 20) & 7u;
    int e4 = (int)(b >> 23) - 127 + 7;
    if (e4 > 15) return s | 0x7Eu;
    return s | ((uint32)e4 << 3) | m3;
}

// uint32 of 4 e4m3 bytes -> two packed-f16 pairs (even bytes {0,2}, odd {1,3}),
// value = e4m3 * 2^-6 (rebias +2 instead of +8 folds the unscale).
__device__ __forceinline__ void dec8(uint32 u, uint32& pe, uint32& po) {
    uint32 se = (u << 8) & 0x80008000u;
    uint32 ue = u & 0x007f007fu;
    pe = ((ue << 7) + 0x08000800u) | se;
    uint32 so = u & 0x80008000u;
    uint32 uo = (u >> 8) & 0x007f007fu;
    po = ((uo << 7) + 0x08000800u) | so;
}

// pack 8 dims (as 4 f16-pairs acc0={d0,d1} acc1={d2,d3} acc2={d4,d5} acc3={d6,d7})
// into the xw byte layout: word0: b0=d0 b1=d2 b2=d1 b3=d3 ; word1: d4 d6 d5 d7.
__device__ __forceinline__ uint2 enc8(h2 a0, h2 a1, h2 a2, h2 a3) {
    uint32 w0 = enc1((float)a0.x * 64.f)
              | (enc1((float)a1.x * 64.f) << 8)
              | (enc1((float)a0.y * 64.f) << 16)
              | (enc1((float)a1.y * 64.f) << 24);
    uint32 w1 = enc1((float)a2.x * 64.f)
              | (enc1((float)a3.x * 64.f) << 8)
              | (enc1((float)a2.y * 64.f) << 16)
              | (enc1((float)a3.y * 64.f) << 24);
    return make_uint2(w0, w1);
}

#define RED_GRP(v)  { v += __shfl_xor(v, 1, 64); v += __shfl_xor(v, 2, 64);  v += __shfl_xor(v, 4, 64);  }

// blocks [0, xw_blocks): xw_fp8 = enc(x*w*64). blocks [xw_blocks, ...): row_ptr.
__global__ void __launch_bounds__(256) prep_kernel(const float4* __restrict__ x,
                                                   const float* __restrict__ w,
                                                   uint2* __restrict__ xw,
                                                   const int* __restrict__ adj_row,
                                                   int* __restrict__ row_ptr,
                                                   int n8, int n, int nadj, int xw_blocks) {
    if ((int)blockIdx.x < xw_blocks) {
        int i = blockIdx.x * blockDim.x + threadIdx.x;   // over n*8 dim-groups
        if (i >= n8) return;
        float s = w[i >> 3] * 64.f;
        float4 a = x[i * 2], b = x[i * 2 + 1];
        // word0: b0=d0 b1=d2 b2=d1 b3=d3 ; word1: b0=d4 b1=d6 b2=d5 b3=d7
        uint32 w0 = enc1(a.x * s) | (enc1(a.z * s) << 8)
                  | (enc1(a.y * s) << 16) | (enc1(a.w * s) << 24);
        uint32 w1 = enc1(b.x * s) | (enc1(b.z * s) << 8)
                  | (enc1(b.y * s) << 16) | (enc1(b.w * s) << 24);
        xw[i] = make_uint2(w0, w1);
    } else {
        int i = (blockIdx.x - xw_blocks) * blockDim.x + threadIdx.x;
        if (i > n) return;
        int lo = 0, hi = nadj;                 // lower_bound(adj_row, i)
        while (lo < hi) {
            int mid = (lo + hi) >> 1;
            if (adj_row[mid] < i) lo = mid + 1; else hi = mid;
        }
        row_ptr[i] = lo;
    }
}

// one_hop = A*xw (fp8 src, packed-f16 accumulate -> fp8 dst); deg = degree.
__global__ void __launch_bounds__(256) spmm1_kernel(const uint2* __restrict__ src,
                                                    const int* __restrict__ row_ptr,
                                                    const int* __restrict__ adj_col,
                                                    uint2* __restrict__ dst,
                                                    float* __restrict__ degout,
                                                    int n) {
    int lane = threadIdx.x & 63;
    int sub = lane & 7;
    int node = blockIdx.x * 32 + (threadIdx.x >> 6) * 8 + (lane >> 3);
    if (node >= n) return;
    int start = row_ptr[node], end = row_ptr[node + 1];
    int deg_n = end - start;
    h2 acc0 = u_as_h2(0u), acc1 = u_as_h2(0u), acc2 = u_as_h2(0u), acc3 = u_as_h2(0u);
    int gbase = lane & 56;
    const int* colp = adj_col + start;
    int base = 0;
    for (; base + 8 <= deg_n; base += 8) {     // full blocks: maskless
        int idx = colp[base + sub];
#pragma unroll
        for (int i = 0; i < 8; ++i) {
            int c = __shfl(idx, gbase + i, 64);
            uint2 qv = src[(size_t)c * 8 + sub];
            uint32 pe, po;
            dec8(qv.x, pe, po);
            acc0 += u_as_h2(pe); acc1 += u_as_h2(po);
            dec8(qv.y, pe, po);
            acc2 += u_as_h2(pe); acc3 += u_as_h2(po);
        }
    }
    if (base < deg_n) {                        // tail block, exec-masked
        int k = base + sub;
        int idx = (k < deg_n) ? colp[k] : 0;
#pragma unroll
        for (int i = 0; i < 8; ++i) {
            if (base + i < deg_n) {
                int c = __shfl(idx, gbase + i, 64);
                uint2 qv = src[(size_t)c * 8 + sub];
                uint32 pe, po;
                dec8(qv.x, pe, po);
                acc0 += u_as_h2(pe); acc1 += u_as_h2(po);
                dec8(qv.y, pe, po);
                acc2 += u_as_h2(pe); acc3 += u_as_h2(po);
            }
        }
    }
    // fp8 re-encode (same layout as xw); |h1| ~ sigma 0.29, clamp@7 unreachable
    dst[(size_t)node * 8 + sub] = enc8(acc0, acc1, acc2, acc3);
    if (sub == 0) degout[node] = (float)deg_n;
}

// two_iter = A*one_hop (fp8 src, packed-f16 acc -> bf16 dst); degpair={deg,deg2}.
__global__ void __launch_bounds__(256) spmm2_kernel(const uint2* __restrict__ src,
                                                    const int* __restrict__ row_ptr,
                                                    const int* __restrict__ adj_col,
                                                    const float* __restrict__ degv,
                                                    uint4* __restrict__ dst,
                                                    float2* __restrict__ degpair,
                                                    int n) {
    int lane = threadIdx.x & 63;
    int sub = lane & 7;
    int node = blockIdx.x * 32 + (threadIdx.x >> 6) * 8 + (lane >> 3);
    if (node >= n) return;
    int start = row_ptr[node], end = row_ptr[node + 1];
    int deg_n = end - start;
    h2 acc0 = u_as_h2(0u), acc1 = u_as_h2(0u), acc2 = u_as_h2(0u), acc3 = u_as_h2(0u);
    float dsum = 0.f;
    int gbase = lane & 56;
    const int* colp = adj_col + start;
    int base = 0;
    for (; base + 8 <= deg_n; base += 8) {     // full blocks: maskless
        int idx = colp[base + sub];
        dsum += degv[idx];
#pragma unroll
        for (int i = 0; i < 8; ++i) {
            int c = __shfl(idx, gbase + i, 64);
            uint2 qv = src[(size_t)c * 8 + sub];
            uint32 pe, po;
            dec8(qv.x, pe, po);
            acc0 += u_as_h2(pe); acc1 += u_as_h2(po);
            dec8(qv.y, pe, po);
            acc2 += u_as_h2(pe); acc3 += u_as_h2(po);
        }
    }
    if (base < deg_n) {                        // tail block, exec-masked
        int k = base + sub;
        bool kv = k < deg_n;
        int idx = kv ? colp[k] : 0;
        if (kv) dsum += degv[idx];
#pragma unroll
        for (int i = 0; i < 8; ++i) {
            if (base + i < deg_n) {
                int c = __shfl(idx, gbase + i, 64);
                uint2 qv = src[(size_t)c * 8 + sub];
                uint32 pe, po;
                dec8(qv.x, pe, po);
                acc0 += u_as_h2(pe); acc1 += u_as_h2(po);
                dec8(qv.y, pe, po);
                acc2 += u_as_h2(pe); acc3 += u_as_h2(po);
            }
        }
    }
    // two_iter stays bf16 (cancellation-sensitive t path keeps 8-bit mantissa)
    uint4 o;
    o.x = pack2((float)acc0.x, (float)acc0.y);
    o.y = pack2((float)acc1.x, (float)acc1.y);
    o.z = pack2((float)acc2.x, (float)acc2.y);
    o.w = pack2((float)acc3.x, (float)acc3.y);
    dst[(size_t)node * 8 + sub] = o;
    RED_GRP(dsum)                              // sum over the group's 8 lanes
    if (sub == 0)
        degpair[node] = make_float2((float)deg_n,
                                    fmaxf(dsum - (float)deg_n - 1.0f, 0.0f));
}

__global__ void __launch_bounds__(256) edge_kernel(const int* __restrict__ edges, // [2,E]
                                                   const uint2* __restrict__ xw,
                                                   const uint2* __restrict__ h1,
                                                   const uint4* __restrict__ t2,
                                                   const float2* __restrict__ degpair,
                                                   float* __restrict__ out,
                                                   int E) {
    __shared__ float so[32 * 15];              // 32 edges/block x 15 features
    int t = blockIdx.x * blockDim.x + threadIdx.x;
    int q = t >> 3, sub = t & 7;               // 8 lanes per edge
    bool valid = q < E;
    if (valid) {
        int u = edges[q], v = edges[E + q];
        uint2 pxu = xw[(size_t)u * 8 + sub], pxv = xw[(size_t)v * 8 + sub];
        uint2 phu = h1[(size_t)u * 8 + sub], phv = h1[(size_t)v * 8 + sub];
        uint4 ptu = t2[(size_t)u * 8 + sub], ptv = t2[(size_t)v * 8 + sub];
        float2 dpu = degpair[u], dpv = degpair[v];
        float du = dpu.x, du2 = dpu.y, dv = dpv.x, dv2 = dpv.y;

        float fxu[8], fxv[8], fhu[8], fhv[8], ftu[8], ftv[8];
        {
            uint32 pe, po;
            h2 e, o_;
#define DEC_F8(P, F)                                                     \
            dec8(P.x, pe, po);                                           \
            e = u_as_h2(pe); o_ = u_as_h2(po);                           \
            F[0] = (float)e.x; F[1] = (float)e.y;                        \
            F[2] = (float)o_.x; F[3] = (float)o_.y;                      \
            dec8(P.y, pe, po);                                           \
            e = u_as_h2(pe); o_ = u_as_h2(po);                           \
            F[4] = (float)e.x; F[5] = (float)e.y;                        \
            F[6] = (float)o_.x; F[7] = (float)o_.y;
            DEC_F8(pxu, fxu)
            DEC_F8(pxv, fxv)
            DEC_F8(phu, fhu)
            DEC_F8(phv, fhv)
#undef DEC_F8
        }
        ftu[0]=lo2f(ptu.x); ftu[1]=hi2f(ptu.x); ftu[2]=lo2f(ptu.y); ftu[3]=hi2f(ptu.y);
        ftu[4]=lo2f(ptu.z); ftu[5]=hi2f(ptu.z); ftu[6]=lo2f(ptu.w); ftu[7]=hi2f(ptu.w);
        ftv[0]=lo2f(ptv.x); ftv[1]=hi2f(ptv.x); ftv[2]=lo2f(ptv.y); ftv[3]=hi2f(ptv.y);
        ftv[4]=lo2f(ptv.z); ftv[5]=hi2f(ptv.z); ftv[6]=lo2f(ptv.w); ftv[7]=hi2f(ptv.w);

        float c11 = 0.f, c12 = 0.f, c21 = 0.f, c22 = 0.f,
              cc12 = 0.f, cc21 = 0.f, cc22 = 0.f, cs12 = 0.f, cs21 = 0.f;
#pragma unroll
        for (int j = 0; j < 8; ++j) {
            float xu = fxu[j], xv = fxv[j];
            float hu = fhu[j], hv = fhv[j];
            float tu = ftu[j], tv = ftv[j];
            float h2u = tu - hu - xu, h2v = tv - hv - xv;
            float au = fmaf(-du, xu, tu), av = fmaf(-dv, xv, tv);
            c11  = fmaf(hu,  hv,  c11);
            c12  = fmaf(hu,  h2v, c12);
            c21  = fmaf(h2u, hv,  c21);
            c22  = fmaf(h2u, h2v, c22);
            cc12 = fmaf(hu,  tv,  cc12);
            cc21 = fmaf(tu,  hv,  cc21);
            cc22 = fmaf(au,  av,  cc22);
            cs12 = fmaf(hu,  tu,  cs12);
            cs21 = fmaf(hv,  tv,  cs21);
        }
        RED_GRP(c11) RED_GRP(c12) RED_GRP(c21) RED_GRP(c22)
        RED_GRP(cc12) RED_GRP(cc21) RED_GRP(cc22) RED_GRP(cs12) RED_GRP(cs21)

        if (sub == 0) {
            float* o = so + (threadIdx.x >> 3) * 15;
            o[0]  = c11;
            o[1]  = c12;
            o[2]  = c21;
            o[3]  = c22;
            o[4]  = du + dv - 2.f * c11 - c12 - c21;
            o[5]  = du2 + dv2 - 2.f * c22 - c12 - c21;
            o[6]  = cc12;
            o[7]  = cc21;
            o[8]  = cc22;
            o[9]  = cs12;
            o[10] = cs21;
            o[11] = du;
            o[12] = dv;
            o[13] = du2;
            o[14] = dv2;
        }
    }
    __syncthreads();
    int eb = blockIdx.x * 32;                  // first edge of this block
    if (eb < E) {
        int nval = E - eb; if (nval > 32) nval = 32;
        int nflt = nval * 15;
        size_t obase = (size_t)eb * 15;
        for (int k = threadIdx.x; k < nflt; k += 256)
            out[obase + k] = so[k];            // fully coalesced
    }
}

extern "C" void kernel_launch(void* const* d_in, const int* in_sizes, int n_in,
                              void* d_out, int out_size, void* d_ws, size_t ws_size,
                              hipStream_t stream) {
    const float* x       = (const float*)d_in[0];
    const float* w       = (const float*)d_in[1];
    const int*   edges   = (const int*)d_in[2];
    const int*   adj_row = (const int*)d_in[3];
    const int*   adj_col = (const int*)d_in[4];

    const int N    = in_sizes[1];        // node_weight length
    const int E    = in_sizes[2] / 2;
    const int NADJ = in_sizes[3];

    char* ws = (char*)d_ws;
    size_t off = 0;
    auto take = [&](size_t bytes) {
        void* p = ws + off;
        off = (off + bytes + 255) & ~(size_t)255;
        return p;
    };
    uint2*  xw      = (uint2*)take((size_t)N * 8 * sizeof(uint2));  // fp8: 64 B/node
    uint2*  one_hop = (uint2*)take((size_t)N * 8 * sizeof(uint2));  // fp8: 64 B/node
    uint4*  two_it  = (uint4*)take((size_t)N * D * 2);              // bf16: 128 B/node
    float*  deg     = (float*)take((size_t)N * sizeof(float));
    float2* degpair = (float2*)take((size_t)N * sizeof(float2));
    int*    row_ptr = (int*)take((size_t)(N + 1) * sizeof(int));
    (void)ws_size;

    float* out = (float*)d_out;

    // 1. fused: xw fp8 encode + CSR row pointers
    {
        int n8 = N * 8;
        int xw_blocks = (n8 + 255) / 256;
        int rp_blocks = (N + 1 + 255) / 256;
        prep_kernel<<<xw_blocks + rp_blocks, 256, 0, stream>>>(
            (const float4*)x, w, xw, adj_row, row_ptr, n8, N, NADJ, xw_blocks);
    }
    // 2. one_hop (fp8) + deg   (32 nodes per 256-thread block)
    spmm1_kernel<<<(N + 31) / 32, 256, 0, stream>>>(xw, row_ptr, adj_col, one_hop, deg, N);
    // 3. two_iter (bf16) + degpair{deg,deg2}
    spmm2_kernel<<<(N + 31) / 32, 256, 0, stream>>>(one_hop, row_ptr, adj_col, deg,
                                                    two_it, degpair, N);
    // 4. edge features
    edge_kernel<<<((size_t)E * 8 + 255) / 256, 256, 0, stream>>>(edges, xw, one_hop, two_it,
                                                                 degpair, out, E);
}